// Round 13
// baseline (55.372 us; speedup 1.0000x reference)
//
#include <hip/hip_runtime.h>
#include <math.h>
#include <stdint.h>

// Router: x (4,8192,1024) f32, W (64,1024) f32
// out = [ top_idx (32768,2) as float | top_gates (32768,2) | loss (1) ]
// ws  = [0,256): expert prob sums | [256,256+384K): frag-major pre-split W
//
// R13: amortize B-operand ingest (the measured ~50us floor of R10-R12).
//  - 256-thr blocks, 4 waves: wave = (ks = K32 half, nh = 32-expert half),
//    each wave: 64 tokens x 32 experts x K32 per tile -> one 6KB W-frag load
//    serves 64 tokens (was 16) -> per-CU W ingest 3MB -> 768KB.
//  - W pre-split frag-major in global (wsplit): each B-fragment is a
//    contiguous 1KB block -> coalesced global_load_dwordx4 into VGPR bank
//    (2x6 short8, double-buffered). W never touches LDS.
//  - x: proven swizzled shared-LDS staging; raw s_barrier + exact counted
//    vmcnt(10) (=4 x-loads + 6 W-loads in flight); drains to 0 only at t=15.
//  - launch_bounds(256,2): measured VGPR cap 256; est ~150 -> no spill.

constexpr int DMODEL = 1024;
constexpr int NEXP   = 64;
constexpr int BM     = 64;    // tokens per block
constexpr int BK     = 64;    // K per tile
constexpr int NTOK   = 32768;
constexpr int NTILE  = DMODEL / BK;  // 16

constexpr int LSTR = 68 * 4;  // logits row stride (bytes)
constexpr size_t WSPLIT_OFF   = 256;
constexpr size_t WSPLIT_BYTES = 384 * 1024;

typedef __attribute__((ext_vector_type(8))) short short8;
typedef __attribute__((ext_vector_type(4))) float f32x4;

__device__ __forceinline__ void gload16(const void* g, void* l) {
    __builtin_amdgcn_global_load_lds(
        (const __attribute__((address_space(1))) unsigned int*)g,
        (__attribute__((address_space(3))) unsigned int*)l,
        16, 0, 0);
}

// split one fp32 into 3 bf16 (truncation chunks; x = h+m+l exact to 2^-24)
__device__ __forceinline__ void split3(float x, short& h, short& m, short& l) {
    uint32_t u  = __float_as_uint(x);
    uint32_t uh = u & 0xffff0000u;
    float    r  = x - __uint_as_float(uh);
    uint32_t ur = __float_as_uint(r);
    uint32_t um = ur & 0xffff0000u;
    float    r2 = r - __uint_as_float(um);
    h = (short)(uh >> 16);
    m = (short)(um >> 16);
    l = (short)(__float_as_uint(r2) >> 16);
}

// ---- W pre-split, FRAG-MAJOR: frag (T,ks,nt,comp) = 1KB block, lane-ordered.
// Frag lane l holds W_comp[e = nt*16+(l&15)][8 k at chunk q = ks*4+(l>>4)].
__global__ void wsplit_kernel(const float* __restrict__ W, char* __restrict__ dst)
{
    const int g = blockIdx.x * 256 + threadIdx.x;   // 0..8191
    const int e = g >> 7;        // expert 0..63
    const int c = g & 127;       // 8-float chunk of the 1024-k row
    const int T   = c >> 3;
    const int q   = c & 7;
    const int ks  = q >> 2;
    const int qhi = q & 3;
    const int lane = (qhi << 4) | (e & 15);
    const int nt   = e >> 4;
    const float* src = W + (size_t)e * DMODEL + c * 8;
    const float4 a = *reinterpret_cast<const float4*>(src);
    const float4 b = *reinterpret_cast<const float4*>(src + 4);
    short8 sH, sM, sL;
    const float v[8] = {a.x, a.y, a.z, a.w, b.x, b.y, b.z, b.w};
#pragma unroll
    for (int j = 0; j < 8; ++j) {
        short h, m, l; split3(v[j], h, m, l);
        sH[j] = h; sM[j] = m; sL[j] = l;
    }
    char* base = dst + ((size_t)((T * 2 + ks) * 4 + nt) * 3) * 1024
                     + (size_t)lane * 16;
    *reinterpret_cast<short8*>(base)        = sH;
    *reinterpret_cast<short8*>(base + 1024) = sM;
    *reinterpret_cast<short8*>(base + 2048) = sL;
}

__global__ __launch_bounds__(256, 2) void router_kernel(
    const float* __restrict__ x, const char* __restrict__ wsAll,
    float* __restrict__ out, float* __restrict__ expert_sums)
{
    // LDS: x dbuf [2][64 rows][256B swizzled] = 32768; epilogue overlay @0;
    // maxArr@32768, invArr@33024, psum@33280
    __shared__ __align__(16) char smem[34304];

    const int tid  = threadIdx.x;
    const int lane = tid & 63;
    const int w    = tid >> 6;   // 0..3
    const int ks   = w & 1;      // K32 half
    const int nh   = w >> 1;     // expert half (2 nt)
    const int tok0 = blockIdx.x * BM;

    f32x4 acc[4][2];
#pragma unroll
    for (int mt = 0; mt < 4; ++mt)
#pragma unroll
        for (int j = 0; j < 2; ++j) acc[mt][j] = (f32x4){0.f, 0.f, 0.f, 0.f};

    // shared x staging (proven swizzle): phys chunk c of row r holds c^(r&15)
    auto stageX = [&](int buf, int tile) {
#pragma unroll
        for (int i = 0; i < 4; ++i) {
            const int flat = i * 256 + tid;
            const int r = flat >> 4;
            const int c = flat & 15;
            const float* src = x + (size_t)(tok0 + r) * DMODEL + tile * BK
                                 + ((c ^ (r & 15)) << 2);
            gload16(src, smem + buf * 16384 + i * 4096 + tid * 16);
        }
    };
    // W frag loads: 6 per tile (2 nt x 3 comp) for this wave's ks
    auto loadW = [&](short8* bank, int tile) {
#pragma unroll
        for (int j = 0; j < 2; ++j)
#pragma unroll
            for (int cp = 0; cp < 3; ++cp) {
                const int fi = ((tile * 2 + ks) * 4 + (nh * 2 + j)) * 3 + cp;
                bank[j * 3 + cp] = *reinterpret_cast<const short8*>(
                    wsAll + (size_t)fi * 1024 + (size_t)lane * 16);
            }
    };

    short8 wb[2][6];
    stageX(0, 0);
    loadW(wb[0], 0);

#pragma unroll
    for (int t = 0; t < NTILE; ++t) {
        if (t + 1 < NTILE) {
            stageX((t + 1) & 1, t + 1);
            loadW(wb[(t + 1) & 1], t + 1);
        }
        // need x(t)+W(t) landed; in flight after them: x(t+1)4 + W(t+1)6 = 10
        if (t < NTILE - 1) asm volatile("s_waitcnt vmcnt(10)" ::: "memory");
        else               asm volatile("s_waitcnt vmcnt(0)"  ::: "memory");
        __builtin_amdgcn_sched_barrier(0);
        __builtin_amdgcn_s_barrier();     // x(t) visible block-wide
        __builtin_amdgcn_sched_barrier(0);

#pragma unroll
        for (int mt = 0; mt < 4; ++mt) {
            const int rl = mt * 16 + (lane & 15);
            const int c0 = ks * 8 + (lane >> 4) * 2;
            const char* xrow = smem + (t & 1) * 16384 + rl * 256;
            const float4 xa = *reinterpret_cast<const float4*>(
                xrow + ((c0 ^ (rl & 15)) << 4));
            const float4 xb = *reinterpret_cast<const float4*>(
                xrow + (((c0 + 1) ^ (rl & 15)) << 4));
            short8 aH, aM, aL;
            {
                const float v[8] = {xa.x, xa.y, xa.z, xa.w, xb.x, xb.y, xb.z, xb.w};
#pragma unroll
                for (int jj = 0; jj < 8; ++jj) {
                    short h, m, l; split3(v[jj], h, m, l);
                    aH[jj] = h; aM[jj] = m; aL[jj] = l;
                }
            }
#pragma unroll
            for (int j = 0; j < 2; ++j) {
                const short8 bH = wb[t & 1][j * 3 + 0];
                const short8 bM = wb[t & 1][j * 3 + 1];
                const short8 bL = wb[t & 1][j * 3 + 2];
                acc[mt][j] = __builtin_amdgcn_mfma_f32_16x16x32_bf16(aH, bH, acc[mt][j], 0, 0, 0);
                acc[mt][j] = __builtin_amdgcn_mfma_f32_16x16x32_bf16(aH, bM, acc[mt][j], 0, 0, 0);
                acc[mt][j] = __builtin_amdgcn_mfma_f32_16x16x32_bf16(aM, bH, acc[mt][j], 0, 0, 0);
                acc[mt][j] = __builtin_amdgcn_mfma_f32_16x16x32_bf16(aH, bL, acc[mt][j], 0, 0, 0);
                acc[mt][j] = __builtin_amdgcn_mfma_f32_16x16x32_bf16(aM, bM, acc[mt][j], 0, 0, 0);
                acc[mt][j] = __builtin_amdgcn_mfma_f32_16x16x32_bf16(aL, bH, acc[mt][j], 0, 0, 0);
            }
        }
        __builtin_amdgcn_sched_barrier(0);
        __builtin_amdgcn_s_barrier();     // all reads of buf done
        __builtin_amdgcn_sched_barrier(0);
    }

    // ---- combine ks halves into LDS logits [64 tok][LSTR] (overlay on xs) ----
    // C/D: col=lane&15 (expert frag), row=(lane>>4)*4+r (verified R10)
    if (ks == 0) {
#pragma unroll
        for (int mt = 0; mt < 4; ++mt)
#pragma unroll
            for (int j = 0; j < 2; ++j)
#pragma unroll
                for (int r = 0; r < 4; ++r) {
                    const int tk = mt * 16 + (lane >> 4) * 4 + r;
                    const int e  = (nh * 2 + j) * 16 + (lane & 15);
                    *reinterpret_cast<float*>(smem + tk * LSTR + e * 4) = acc[mt][j][r];
                }
    }
    __syncthreads();
    if (ks == 1) {
#pragma unroll
        for (int mt = 0; mt < 4; ++mt)
#pragma unroll
            for (int j = 0; j < 2; ++j)
#pragma unroll
                for (int r = 0; r < 4; ++r) {
                    const int tk = mt * 16 + (lane >> 4) * 4 + r;
                    const int e  = (nh * 2 + j) * 16 + (lane & 15);
                    float* p = reinterpret_cast<float*>(smem + tk * LSTR + e * 4);
                    *p += acc[mt][j][r];
                }
    }
    __syncthreads();

    float* maxArr = reinterpret_cast<float*>(smem + 32768);
    float* invArr = reinterpret_cast<float*>(smem + 33024);
    float* psum   = reinterpret_cast<float*>(smem + 33280);

    // pass 1: per-token max, softmax denom, top-2, outputs (threads 0..63)
    if (tid < BM) {
        const char* lrow = smem + tid * LSTR;
        float4 L[16];
#pragma unroll
        for (int i = 0; i < 16; ++i)
            L[i] = *reinterpret_cast<const float4*>(lrow + i * 16);

        float mx = -INFINITY;
#pragma unroll
        for (int i = 0; i < 16; ++i)
            mx = fmaxf(mx, fmaxf(fmaxf(L[i].x, L[i].y), fmaxf(L[i].z, L[i].w)));

        float v0 = -INFINITY, v1 = -INFINITY;
        int   i0 = NEXP, i1 = NEXP;
        float s = 0.f;
#pragma unroll
        for (int i = 0; i < 16; ++i) {
            const float vv[4] = {L[i].x, L[i].y, L[i].z, L[i].w};
#pragma unroll
            for (int c = 0; c < 4; ++c) {
                const float v = vv[c];
                const int  gi = i * 4 + c;
                s += __expf(v - mx);
                if (v > v0) { v1 = v0; i1 = i0; v0 = v; i0 = gi; }
                else if (v > v1) { v1 = v; i1 = gi; }
            }
        }
        maxArr[tid] = mx;
        invArr[tid] = 1.0f / s;

        const float q = __expf(v1 - v0);
        const float d = 1.0f + q;
        const size_t tok = (size_t)tok0 + tid;
        reinterpret_cast<float2*>(out)[tok]            = make_float2((float)i0, (float)i1);
        reinterpret_cast<float2*>(out + 2 * NTOK)[tok] = make_float2(1.0f / d, q / d);
    }
    __syncthreads();

    // pass 2: per-expert prob sums (256 thr: e = tid&63, grp = tid>>6, 16 tok)
    {
        const int e = tid & 63, grp = tid >> 6;
        float s = 0.f;
#pragma unroll
        for (int i = 0; i < 16; ++i) {
            const int tk = grp * 16 + i;
            const float lg = *reinterpret_cast<const float*>(smem + tk * LSTR + e * 4);
            s += __expf(lg - maxArr[tk]) * invArr[tk];
        }
        psum[grp * 64 + e] = s;
    }
    __syncthreads();
    if (tid < 64) {
        const float s = (psum[tid] + psum[64 + tid]) + (psum[128 + tid] + psum[192 + tid]);
        atomicAdd(&expert_sums[tid], s);
    }
}

// ========== fallback (ws too small): R11 kernel (512 thr, LDS W) ==========
constexpr int FXS   = 0;
constexpr int FXSB  = 64 * 64 * 4;
constexpr int FWS   = 32768;
constexpr int FWSB  = 3 * 64 * 64 * 2;
constexpr int FWCMP = 64 * 64 * 2;

__global__ __launch_bounds__(512, 2) void router_fallback(
    const float* __restrict__ x, const float* __restrict__ W,
    float* __restrict__ out, float* __restrict__ expert_sums)
{
    __shared__ __align__(16) char smem[81920];

    const int tid  = threadIdx.x;
    const int lane = tid & 63;
    const int w    = tid >> 6;
    const int mt   = w & 3;
    const int kh   = w >> 2;
    const int tok0 = blockIdx.x * BM;

    f32x4 acc[4];
#pragma unroll
    for (int nt = 0; nt < 4; ++nt) acc[nt] = (f32x4){0.f, 0.f, 0.f, 0.f};

    auto stageX = [&](int buf, int tile) {
#pragma unroll
        for (int i = 0; i < 2; ++i) {
            const int r0 = w * 8 + i * 4;
            const int r  = r0 + (lane >> 4);
            const int c  = lane & 15;
            const float* src = x + (size_t)(tok0 + r) * DMODEL + tile * BK
                                 + ((c ^ (r & 15)) << 2);
            gload16(src, smem + FXS + buf * FXSB + r0 * 256 + (lane << 4));
        }
    };

    const int we  = tid >> 3;
    const int wc  = tid & 7;
    const int wph = wc ^ (we & 7);
    const float* wgp = W + (size_t)we * DMODEL + wc * 8;

    auto convW = [&](int buf, float4 a, float4 b) {
        short8 sH, sM, sL;
        float v[8] = {a.x, a.y, a.z, a.w, b.x, b.y, b.z, b.w};
#pragma unroll
        for (int j = 0; j < 8; ++j) {
            short h, m, l; split3(v[j], h, m, l);
            sH[j] = h; sM[j] = m; sL[j] = l;
        }
        char* d = smem + FWS + buf * FWSB + we * 128 + wph * 16;
        *reinterpret_cast<short8*>(d)            = sH;
        *reinterpret_cast<short8*>(d + FWCMP)    = sM;
        *reinterpret_cast<short8*>(d + 2 * FWCMP) = sL;
    };

    stageX(0, 0);
    {
        float4 a = *reinterpret_cast<const float4*>(wgp);
        float4 b = *reinterpret_cast<const float4*>(wgp + 4);
        convW(0, a, b);
    }
    __syncthreads();

    int buf = 0;
    for (int tile = 0; tile < NTILE; ++tile) {
        float4 wa, wb;
        if (tile + 1 < NTILE) {
            stageX(buf ^ 1, tile + 1);
            wa = *reinterpret_cast<const float4*>(wgp + (tile + 1) * BK);
            wb = *reinterpret_cast<const float4*>(wgp + (tile + 1) * BK + 4);
        }
        {
            const int ksl = kh;
            const int rl = mt * 16 + (lane & 15);
            const int c0 = ksl * 8 + (lane >> 4) * 2;
            const char* xrow = smem + FXS + buf * FXSB + rl * 256;
            const float4 xa = *reinterpret_cast<const float4*>(
                xrow + ((c0 ^ (rl & 15)) << 4));
            const float4 xb = *reinterpret_cast<const float4*>(
                xrow + (((c0 + 1) ^ (rl & 15)) << 4));
            short8 aH, aM, aL;
            {
                float v[8] = {xa.x, xa.y, xa.z, xa.w, xb.x, xb.y, xb.z, xb.w};
#pragma unroll
                for (int j = 0; j < 8; ++j) {
                    short h, m, l; split3(v[j], h, m, l);
                    aH[j] = h; aM[j] = m; aL[j] = l;
                }
            }
#pragma unroll
            for (int nt = 0; nt < 4; ++nt) {
                const int ef = nt * 16 + (lane & 15);
                const int q  = ksl * 4 + (lane >> 4);
                const char* wrow = smem + FWS + buf * FWSB + ef * 128
                                 + ((q ^ (ef & 7)) << 4);
                const short8 bH = *reinterpret_cast<const short8*>(wrow);
                const short8 bM = *reinterpret_cast<const short8*>(wrow + FWCMP);
                const short8 bL = *reinterpret_cast<const short8*>(wrow + 2 * FWCMP);
                acc[nt] = __builtin_amdgcn_mfma_f32_16x16x32_bf16(aH, bH, acc[nt], 0, 0, 0);
                acc[nt] = __builtin_amdgcn_mfma_f32_16x16x32_bf16(aH, bM, acc[nt], 0, 0, 0);
                acc[nt] = __builtin_amdgcn_mfma_f32_16x16x32_bf16(aM, bH, acc[nt], 0, 0, 0);
                acc[nt] = __builtin_amdgcn_mfma_f32_16x16x32_bf16(aH, bL, acc[nt], 0, 0, 0);
                acc[nt] = __builtin_amdgcn_mfma_f32_16x16x32_bf16(aM, bM, acc[nt], 0, 0, 0);
                acc[nt] = __builtin_amdgcn_mfma_f32_16x16x32_bf16(aL, bH, acc[nt], 0, 0, 0);
            }
        }
        if (tile + 1 < NTILE) convW(buf ^ 1, wa, wb);
        __syncthreads();
        buf ^= 1;
    }

    if (kh == 0) {
#pragma unroll
        for (int nt = 0; nt < 4; ++nt)
#pragma unroll
            for (int r = 0; r < 4; ++r) {
                const int t = mt * 16 + (lane >> 4) * 4 + r;
                const int e = nt * 16 + (lane & 15);
                *reinterpret_cast<float*>(smem + t * LSTR + e * 4) = acc[nt][r];
            }
    }
    __syncthreads();
    if (kh == 1) {
#pragma unroll
        for (int nt = 0; nt < 4; ++nt)
#pragma unroll
            for (int r = 0; r < 4; ++r) {
                const int t = mt * 16 + (lane >> 4) * 4 + r;
                const int e = nt * 16 + (lane & 15);
                float* p = reinterpret_cast<float*>(smem + t * LSTR + e * 4);
                *p += acc[nt][r];
            }
    }
    __syncthreads();

    float* maxArr = reinterpret_cast<float*>(smem + 18432);
    float* invArr = reinterpret_cast<float*>(smem + 18688);
    float* psum   = reinterpret_cast<float*>(smem + 18944);

    if (tid < BM) {
        const char* lrow = smem + tid * LSTR;
        float4 L[16];
#pragma unroll
        for (int i = 0; i < 16; ++i)
            L[i] = *reinterpret_cast<const float4*>(lrow + i * 16);
        float mx = -INFINITY;
#pragma unroll
        for (int i = 0; i < 16; ++i)
            mx = fmaxf(mx, fmaxf(fmaxf(L[i].x, L[i].y), fmaxf(L[i].z, L[i].w)));
        float v0 = -INFINITY, v1 = -INFINITY;
        int   i0 = NEXP, i1 = NEXP;
        float s = 0.f;
#pragma unroll
        for (int i = 0; i < 16; ++i) {
            const float vv[4] = {L[i].x, L[i].y, L[i].z, L[i].w};
#pragma unroll
            for (int c = 0; c < 4; ++c) {
                const float v = vv[c];
                const int  gi = i * 4 + c;
                s += __expf(v - mx);
                if (v > v0) { v1 = v0; i1 = i0; v0 = v; i0 = gi; }
                else if (v > v1) { v1 = v; i1 = gi; }
            }
        }
        maxArr[tid] = mx;
        invArr[tid] = 1.0f / s;
        const float q = __expf(v1 - v0);
        const float d = 1.0f + q;
        const size_t tok = (size_t)tok0 + tid;
        reinterpret_cast<float2*>(out)[tok]            = make_float2((float)i0, (float)i1);
        reinterpret_cast<float2*>(out + 2 * NTOK)[tok] = make_float2(1.0f / d, q / d);
    }
    __syncthreads();
    {
        const int e = tid & 63, grp = tid >> 6;
        float s = 0.f;
#pragma unroll
        for (int i = 0; i < 8; ++i) {
            const int t = grp * 8 + i;
            const float lg = *reinterpret_cast<const float*>(smem + t * LSTR + e * 4);
            s += __expf(lg - maxArr[t]) * invArr[t];
        }
        psum[grp * 64 + e] = s;
    }
    __syncthreads();
    if (tid < 64) {
        float s = 0.f;
#pragma unroll
        for (int g = 0; g < 8; ++g) s += psum[g * 64 + tid];
        atomicAdd(&expert_sums[tid], s);
    }
}

__global__ void loss_kernel(const float* __restrict__ sums, float* __restrict__ out)
{
    const int lane = threadIdx.x;  // 64 threads
    float pv = sums[lane] * (1.0f / (float)NTOK);  // avg_probs[lane]
    float m = pv;
#pragma unroll
    for (int off = 32; off; off >>= 1) m += __shfl_xor(m, off, 64);
    m *= (1.0f / (float)NEXP);
    float d = pv - m;
    float v = d * d;
#pragma unroll
    for (int off = 32; off; off >>= 1) v += __shfl_xor(v, off, 64);
    v *= (1.0f / (float)(NEXP - 1));  // ddof=1
    if (lane == 0) {
        float stdv = sqrtf(v);
        float r = stdv / (m + 1e-6f);
        out[4 * NTOK] = r * r;
    }
}

extern "C" void kernel_launch(void* const* d_in, const int* in_sizes, int n_in,
                              void* d_out, int out_size, void* d_ws, size_t ws_size,
                              hipStream_t stream)
{
    const float* x = (const float*)d_in[0];
    const float* W = (const float*)d_in[1];
    float* out  = (float*)d_out;
    float* sums = (float*)d_ws;

    hipMemsetAsync(d_ws, 0, 256, stream);

    if (ws_size >= WSPLIT_OFF + WSPLIT_BYTES) {
        char* wsAll = (char*)d_ws + WSPLIT_OFF;
        hipLaunchKernelGGL(wsplit_kernel, dim3(32), dim3(256), 0, stream, W, wsAll);
        hipLaunchKernelGGL(router_kernel, dim3(NTOK / BM), dim3(256), 0, stream,
                           x, wsAll, out, sums);
    } else {
        hipLaunchKernelGGL(router_fallback, dim3(NTOK / BM), dim3(512), 0, stream,
                           x, W, out, sums);
    }
    hipLaunchKernelGGL(loss_kernel, dim3(1), dim3(64), 0, stream, sums, out);
}